// Round 5
// baseline (71.344 us; speedup 1.0000x reference)
//
#include <hip/hip_runtime.h>
#include <math.h>

// ChADALINE: out[b,o] = sigmoid( (sum_i x[b,i]*W[i,o] + sum_i bias[i,o]) / IN )
// Choquet integral w/ cardinality measure == arithmetic mean; sort eliminated.
//
// R5: gemm uses 32x32 tiles, 256 blocks = exactly 1/CU. Halves fragment read
// traffic vs R4 (96 MB -> 48 MB). Same proven structure: fragments pre-packed
// by prep in exact MFMA order, all loads issued up front (deep MLP, no K-loop,
// no barriers before epilogue), split-K-4 across waves, bias folded as
// ones-MFMA, LDS reduce + sigmoid + float4 store epilogue.

#define BATCH   256
#define IN_DIM  1024
#define OUT_DIM 1024

// ws layout (bytes)
#define APACK_OFF 0                    // [16 mt16][32 s][64 lane][8] bf16 = 512 KB
#define WPACK_OFF (512 * 1024)         // [64 nt16][64 s][64 lane][8] bf16 = 4 MB
                                       //   s<32: from w, s>=32: from bias

#define NWTASK_A   512                 // 16 mt16 * 32 s
#define NWTASK_W  4096                 // 64 nt16 * 64 s (w + bias)
#define NBLK_PREP ((NWTASK_A + NWTASK_W) / 4)   // 1152

typedef __bf16 bf16x8 __attribute__((ext_vector_type(8)));
typedef float  f32x4  __attribute__((ext_vector_type(4)));

__global__ __launch_bounds__(256) void chad_prep(
    const float* __restrict__ x,     // [BATCH, IN_DIM]
    const float* __restrict__ w,     // [IN_DIM, OUT_DIM]
    const float* __restrict__ bias,  // [IN_DIM, OUT_DIM]
    unsigned char* __restrict__ ws)
{
    __bf16* apack = (__bf16*)(ws + APACK_OFF);
    __bf16* wpack = (__bf16*)(ws + WPACK_OFF);

    const int t    = threadIdx.x;
    const int lane = t & 63;
    const int wv   = t >> 6;
    const int g    = blockIdx.x * 4 + wv;   // global wave-task id
    const int l16  = lane & 15;
    const int quad = lane >> 4;

    if (g < NWTASK_A) {
        // pack x[mt16*16 + l16][s*32 + quad*8 + j] -> apack[g][lane][j]
        const int mt = g >> 5, s = g & 31;
        const float* src = x + (size_t)(mt * 16 + l16) * IN_DIM + s * 32 + quad * 8;
        const float4 v0 = *(const float4*)src;
        const float4 v1 = *(const float4*)(src + 4);
        bf16x8 o;
        o[0] = (__bf16)v0.x; o[1] = (__bf16)v0.y; o[2] = (__bf16)v0.z; o[3] = (__bf16)v0.w;
        o[4] = (__bf16)v1.x; o[5] = (__bf16)v1.y; o[6] = (__bf16)v1.z; o[7] = (__bf16)v1.w;
        *(bf16x8*)(apack + (size_t)g * 512 + lane * 8) = o;
    } else {
        // pack src[k + quad*8 + j][nt16*16 + l16] -> wpack[nt16*64+s][lane][j]
        // s<32: src=w, k=s*32; s>=32: src=bias, k=(s-32)*32
        const int wt = g - NWTASK_A;        // 0..4095
        const int nt = wt >> 6, s = wt & 63;
        const float* base = (s < 32) ? w : bias;
        const int k = (s & 31) * 32;
        const float* src = base + (size_t)(k + quad * 8) * OUT_DIM + nt * 16 + l16;
        bf16x8 o;
        #pragma unroll
        for (int j = 0; j < 8; ++j) o[j] = (__bf16)src[(size_t)j * OUT_DIM];
        *(bf16x8*)(wpack + (size_t)wt * 512 + lane * 8) = o;
    }
}

__global__ __launch_bounds__(256, 1) void chad_gemm(
    const unsigned char* __restrict__ ws,
    float* __restrict__ out)          // [BATCH, OUT_DIM]
{
    const __bf16* apack = (const __bf16*)(ws + APACK_OFF);
    const __bf16* wpack = (const __bf16*)(ws + WPACK_OFF);

    // red[wave][acc][lane][reg]; acc 0..3 = subtile r*2+c, acc 4..5 = bias col c
    __shared__ float red[4][6][64][4];   // 24 KB

    const int t    = threadIdx.x;
    const int lane = t & 63;
    const int wv   = t >> 6;                 // split-K segment
    const int mt   = blockIdx.x >> 5;        // 0..7  : 32-row tile
    const int nt   = blockIdx.x & 31;        // 0..31 : 32-col tile

    // ---- A fragments: sub-rows r=0,1, chunks i=0..7 (s = wv*8+i)
    const __bf16* ab = apack + ((size_t)((mt * 2) * 32 + wv * 8) * 64 + lane) * 8;
    bf16x8 af[2][8];
    #pragma unroll
    for (int r = 0; r < 2; ++r)
        #pragma unroll
        for (int i = 0; i < 8; ++i)
            af[r][i] = *(const bf16x8*)(ab + ((size_t)r * 32 + i) * 512);

    bf16x8 one8;
    #pragma unroll
    for (int j = 0; j < 8; ++j) one8[j] = (__bf16)1.0f;

    f32x4 accw[2][2] = {{{0.f,0.f,0.f,0.f},{0.f,0.f,0.f,0.f}},
                        {{0.f,0.f,0.f,0.f},{0.f,0.f,0.f,0.f}}};
    f32x4 accb[2]    = {{0.f,0.f,0.f,0.f},{0.f,0.f,0.f,0.f}};

    // ---- per sub-col c: load W + bias fragments, MFMA
    #pragma unroll
    for (int c = 0; c < 2; ++c) {
        const __bf16* wb = wpack + ((size_t)((nt * 2 + c) * 64 + wv * 8) * 64 + lane) * 8;
        bf16x8 wf[8], bf8[8];
        #pragma unroll
        for (int i = 0; i < 8; ++i) wf[i]  = *(const bf16x8*)(wb + (size_t)i * 512);
        #pragma unroll
        for (int i = 0; i < 8; ++i) bf8[i] = *(const bf16x8*)(wb + (size_t)(32 + i) * 512);
        #pragma unroll
        for (int i = 0; i < 8; ++i) {
            accw[0][c] = __builtin_amdgcn_mfma_f32_16x16x32_bf16(af[0][i], wf[i], accw[0][c], 0, 0, 0);
            accw[1][c] = __builtin_amdgcn_mfma_f32_16x16x32_bf16(af[1][i], wf[i], accw[1][c], 0, 0, 0);
            accb[c]    = __builtin_amdgcn_mfma_f32_16x16x32_bf16(one8,     bf8[i], accb[c],   0, 0, 0);
        }
    }

    #pragma unroll
    for (int r = 0; r < 2; ++r)
        #pragma unroll
        for (int c = 0; c < 2; ++c)
            *(f32x4*)&red[wv][r * 2 + c][lane][0] = accw[r][c];
    #pragma unroll
    for (int c = 0; c < 2; ++c)
        *(f32x4*)&red[wv][4 + c][lane][0] = accb[c];
    __syncthreads();

    // ---- epilogue: thread t -> row = t>>3 (0..31), cols 4*(t&7) .. +3
    // C/D layout within a 16x16 subtile: value (row16,col16) lives in
    // lane ((row16>>2)<<4) + col16, reg row16&3. Bias colsum from row16=0.
    const int row  = t >> 3;
    const int cb   = (t & 7) * 4;
    const int r    = row >> 4;
    const int row16 = row & 15;
    const int rr   = row16 & 3;
    const int rlh  = (row16 >> 2) << 4;
    const float inv_n = 1.0f / (float)IN_DIM;

    float4 o;
    #pragma unroll
    for (int j = 0; j < 4; ++j) {
        const int col   = cb + j;
        const int c     = col >> 4;
        const int col16 = col & 15;
        const int a     = r * 2 + c;
        float v  = red[0][a][rlh + col16][rr] + red[1][a][rlh + col16][rr]
                 + red[2][a][rlh + col16][rr] + red[3][a][rlh + col16][rr];
        float cs = red[0][4 + c][col16][0] + red[1][4 + c][col16][0]
                 + red[2][4 + c][col16][0] + red[3][4 + c][col16][0];
        const float z = (v + cs) * inv_n;
        (&o.x)[j] = 1.0f / (1.0f + __expf(-z));
    }
    *(float4*)&out[(size_t)(mt * 32 + row) * OUT_DIM + nt * 32 + cb] = o;
}

extern "C" void kernel_launch(void* const* d_in, const int* in_sizes, int n_in,
                              void* d_out, int out_size, void* d_ws, size_t ws_size,
                              hipStream_t stream) {
    const float* x  = (const float*)d_in[0];
    const float* w  = (const float*)d_in[1];
    const float* b  = (const float*)d_in[2];
    float* out = (float*)d_out;

    chad_prep<<<NBLK_PREP, 256, 0, stream>>>(x, w, b, (unsigned char*)d_ws);
    chad_gemm<<<(BATCH / 32) * (OUT_DIM / 32), 256, 0, stream>>>(
        (const unsigned char*)d_ws, out);
}